// Round 2
// baseline (147.862 us; speedup 1.0000x reference)
//
#include <hip/hip_runtime.h>
#include <stdint.h>

constexpr int Tn = 4, Bn = 8, Cn = 64, Hn = 128, Wn = 128;
constexpr int HsC = 64, WsC = 64;
constexpr int Kn = 256;                 // C * r^2
constexpr int PX = HsC * WsC;           // 4096 pixels per (t,b) plane
constexpr float DECAYF = 0.25f;

typedef __attribute__((ext_vector_type(8))) short short8v;
typedef __attribute__((ext_vector_type(4))) float f32x4;

static __device__ __forceinline__ ushort f2bf_rn(float f) {
    uint32_t u = __float_as_uint(f);
    uint32_t r = (u + 0x7FFFu + ((u >> 16) & 1u)) >> 16;
    return (ushort)r;
}
static __device__ __forceinline__ float bf2f(ushort u) {
    return __uint_as_float(((uint32_t)u) << 16);
}

// ---------------------------------------------------------------------------
// Kernel 0: weight prep — fold /4 dequant, split into bf16 hi + lo
// ---------------------------------------------------------------------------
__global__ __launch_bounds__(256) void wprep_kernel(const float* __restrict__ w,
                                                    ushort* __restrict__ wh,
                                                    ushort* __restrict__ wl) {
    int i = blockIdx.x * 256 + threadIdx.x;     // 16384 total
    float wq = w[i] * 0.25f;
    ushort h = f2bf_rn(wq);
    float hf = bf2f(h);
    wh[i] = h;
    wl[i] = f2bf_rn(wq - hf);
}

// ---------------------------------------------------------------------------
// Kernel 1: PixelUnshuffle + LIF scan -> u8 spikes, PX-MAJOR: sp[tb][px][k]
// thread = (b, cg of 16 c, hs, ws); per pixel writes 64B contiguous (16 c x 4 p)
// ---------------------------------------------------------------------------
__global__ __launch_bounds__(256) void lif_kernel(const float* __restrict__ x,
                                                  uint8_t* __restrict__ sp) {
    int tid = threadIdx.x;
    int ws = tid & 63;
    int hs_lo = tid >> 6;              // 0..3
    int bi = blockIdx.x;               // 512 blocks
    int hs_hi = bi & 15;
    int cg = (bi >> 4) & 3;
    int b = bi >> 6;                   // 0..7
    int hs = hs_hi * 4 + hs_lo;
    int c0 = cg * 16;

    float mem[16], spk[16];
    #pragma unroll
    for (int i = 0; i < 16; ++i) { mem[i] = 0.f; spk[i] = 0.f; }

    #pragma unroll
    for (int t = 0; t < 4; ++t) {
        uint32_t pk[16];
        #pragma unroll
        for (int ci = 0; ci < 16; ++ci) {
            const float* xr = x + (((size_t)(t * Bn + b) * Cn + (c0 + ci)) * (Hn * Wn))
                                + (2 * hs) * Wn + 2 * ws;
            float2 r0 = *(const float2*)xr;
            float2 r1 = *(const float2*)(xr + Wn);
            float m = mem[ci], s = spk[ci];
            uint32_t pkv;
            float sv;
            m = (m - s) * DECAYF + r0.x;
            sv = rintf(fminf(fmaxf(m, 0.f), 4.f)); s = sv * 0.25f;
            pkv = (uint32_t)(int)sv;
            m = (m - s) * DECAYF + r0.y;
            sv = rintf(fminf(fmaxf(m, 0.f), 4.f)); s = sv * 0.25f;
            pkv |= ((uint32_t)(int)sv) << 8;
            m = (m - s) * DECAYF + r1.x;
            sv = rintf(fminf(fmaxf(m, 0.f), 4.f)); s = sv * 0.25f;
            pkv |= ((uint32_t)(int)sv) << 16;
            m = (m - s) * DECAYF + r1.y;
            sv = rintf(fminf(fmaxf(m, 0.f), 4.f)); s = sv * 0.25f;
            pkv |= ((uint32_t)(int)sv) << 24;
            mem[ci] = m; spk[ci] = s; pk[ci] = pkv;
        }
        int px = hs * 64 + ws;
        uint8_t* dst = sp + ((size_t)(t * Bn + b) * PX + px) * Kn + c0 * 4;
        ((uint4*)dst)[0] = make_uint4(pk[0], pk[1], pk[2], pk[3]);
        ((uint4*)dst)[1] = make_uint4(pk[4], pk[5], pk[6], pk[7]);
        ((uint4*)dst)[2] = make_uint4(pk[8], pk[9], pk[10], pk[11]);
        ((uint4*)dst)[3] = make_uint4(pk[12], pk[13], pk[14], pk[15]);
    }
}

// ---------------------------------------------------------------------------
// u8 spikes (0..4) -> 8 bf16 via v_perm byte-LUT (exact)
// bf16: 0->0x0000 1->0x3F80 2->0x4000 3->0x4040 4->0x4080
// ---------------------------------------------------------------------------
static __device__ __forceinline__ short8v unpack8(uint32_t s0, uint32_t s1) {
    uint32_t lo0 = __builtin_amdgcn_perm(0x00000080u, 0x40008000u, s0);
    uint32_t hi0 = __builtin_amdgcn_perm(0x00000040u, 0x40403F00u, s0);
    uint32_t lo1 = __builtin_amdgcn_perm(0x00000080u, 0x40008000u, s1);
    uint32_t hi1 = __builtin_amdgcn_perm(0x00000040u, 0x40403F00u, s1);
    union { uint32_t u[4]; short8v s; } r;
    r.u[0] = __builtin_amdgcn_perm(hi0, lo0, 0x05010400u);
    r.u[1] = __builtin_amdgcn_perm(hi0, lo0, 0x07030602u);
    r.u[2] = __builtin_amdgcn_perm(hi1, lo1, 0x05010400u);
    r.u[3] = __builtin_amdgcn_perm(hi1, lo1, 0x07030602u);
    return r.s;
}

// ---------------------------------------------------------------------------
// Kernel 2: MFMA conv at low res. Per (t,b): y[c][px] = sum_k wq[c][k]*sv[k][px]
// M=64 N=4096 K=256. Wave = 4 m-tiles x 2 n-tiles (64c x 32px), block = 4 waves.
// A (w hi/lo) frags: contiguous 16B from global (L1/L2). B frags: contiguous 8B
// u8 from px-major spikes + perm-LUT. No LDS.
// ---------------------------------------------------------------------------
__global__ __launch_bounds__(256) void conv_mfma(const uint8_t* __restrict__ sp,
                                                 const ushort* __restrict__ wh,
                                                 const ushort* __restrict__ wl,
                                                 ushort* __restrict__ y) {
    int tid = threadIdx.x;
    int lane = tid & 63;
    int wid = tid >> 6;
    int l15 = lane & 15;
    int g = lane >> 4;

    int tb = blockIdx.x >> 5;               // 0..31
    int px0w = (blockIdx.x & 31) * 128 + wid * 32;

    const uint8_t* spb = sp + (size_t)tb * PX * Kn;

    f32x4 acc[4][2];
    #pragma unroll
    for (int mt = 0; mt < 4; ++mt)
        #pragma unroll
        for (int nt = 0; nt < 2; ++nt)
            acc[mt][nt] = (f32x4){0.f, 0.f, 0.f, 0.f};

    #pragma unroll
    for (int ks = 0; ks < 8; ++ks) {
        int k0 = ks * 32 + g * 8;
        short8v ah[4], al[4];
        #pragma unroll
        for (int mt = 0; mt < 4; ++mt) {
            int row = mt * 16 + l15;
            ah[mt] = *(const short8v*)(wh + row * Kn + k0);
            al[mt] = *(const short8v*)(wl + row * Kn + k0);
        }
        #pragma unroll
        for (int nt = 0; nt < 2; ++nt) {
            int px = px0w + nt * 16 + l15;
            const uint8_t* p8 = spb + (size_t)px * Kn + k0;
            uint32_t s0 = *(const uint32_t*)p8;
            uint32_t s1 = *(const uint32_t*)(p8 + 4);
            short8v bf = unpack8(s0, s1);
            #pragma unroll
            for (int mt = 0; mt < 4; ++mt) {
                acc[mt][nt] = __builtin_amdgcn_mfma_f32_16x16x32_bf16(ah[mt], bf, acc[mt][nt], 0, 0, 0);
                acc[mt][nt] = __builtin_amdgcn_mfma_f32_16x16x32_bf16(al[mt], bf, acc[mt][nt], 0, 0, 0);
            }
        }
    }

    // epilogue: C/D layout col=lane&15 (px), row=(lane>>4)*4+reg (c)
    ushort* yb = y + (size_t)tb * Cn * PX;
    #pragma unroll
    for (int mt = 0; mt < 4; ++mt) {
        #pragma unroll
        for (int nt = 0; nt < 2; ++nt) {
            int px = px0w + nt * 16 + l15;
            #pragma unroll
            for (int r = 0; r < 4; ++r) {
                int c = mt * 16 + g * 4 + r;
                yb[(size_t)c * PX + px] = f2bf_rn(acc[mt][nt][r]);
            }
        }
    }
}

// ---------------------------------------------------------------------------
// Kernel 3: bilinear 2x upsample from bf16 y, half-pixel centers, edge clamp
// ---------------------------------------------------------------------------
__global__ __launch_bounds__(256) void upsample_kernel(const ushort* __restrict__ y,
                                                       float* __restrict__ out) {
    int gg = blockIdx.x * 256 + threadIdx.x;   // 8388608 threads
    int wq = gg & 31;                // output col quad: w0 = 4*wq
    int h  = (gg >> 5) & 127;
    int rr = gg >> 12;
    int c  = rr & 63;
    int tb = rr >> 6;

    const ushort* yp = y + ((size_t)tb * Cn + c) * PX;

    int m = h >> 1;
    int r0, r1; float v0, v1;
    if ((h & 1) == 0) { r0 = (m - 1 < 0) ? 0 : (m - 1); r1 = m; v0 = 0.25f; v1 = 0.75f; }
    else              { r0 = m; r1 = (m + 1 > 63) ? 63 : (m + 1); v0 = 0.75f; v1 = 0.25f; }

    int ca = (2 * wq - 1 < 0) ? 0 : (2 * wq - 1);
    int cb = 2 * wq;
    int cc = 2 * wq + 1;
    int cd = (2 * wq + 2 > 63) ? 63 : (2 * wq + 2);

    const ushort* ra = yp + r0 * WsC;
    const ushort* rb = yp + r1 * WsC;
    float a0 = bf2f(ra[ca]), b0 = bf2f(ra[cb]), e0 = bf2f(ra[cc]), d0 = bf2f(ra[cd]);
    float a1 = bf2f(rb[ca]), b1 = bf2f(rb[cb]), e1 = bf2f(rb[cc]), d1 = bf2f(rb[cd]);

    float h00 = 0.25f * a0 + 0.75f * b0;
    float h01 = 0.75f * b0 + 0.25f * e0;
    float h02 = 0.25f * b0 + 0.75f * e0;
    float h03 = 0.75f * e0 + 0.25f * d0;
    float h10 = 0.25f * a1 + 0.75f * b1;
    float h11 = 0.75f * b1 + 0.25f * e1;
    float h12 = 0.25f * b1 + 0.75f * e1;
    float h13 = 0.75f * e1 + 0.25f * d1;

    float4 o;
    o.x = v0 * h00 + v1 * h10;
    o.y = v0 * h01 + v1 * h11;
    o.z = v0 * h02 + v1 * h12;
    o.w = v0 * h03 + v1 * h13;

    *(float4*)(out + ((size_t)tb * Cn + c) * (Hn * Wn) + (size_t)h * Wn + 4 * wq) = o;
}

// ---------------------------------------------------------------------------
extern "C" void kernel_launch(void* const* d_in, const int* in_sizes, int n_in,
                              void* d_out, int out_size, void* d_ws, size_t ws_size,
                              hipStream_t stream) {
    const float* x = (const float*)d_in[0];
    const float* w = (const float*)d_in[1];
    float* out = (float*)d_out;

    uint8_t* sp = (uint8_t*)d_ws;                                   // 33,554,432 B
    ushort*  y  = (ushort*)((uint8_t*)d_ws + (size_t)33554432);     // 16,777,216 B
    ushort*  whi = (ushort*)((uint8_t*)d_ws + (size_t)50331648);    // 32,768 B
    ushort*  wlo = (ushort*)((uint8_t*)d_ws + (size_t)50364416);    // 32,768 B

    wprep_kernel<<<64, 256, 0, stream>>>(w, whi, wlo);
    lif_kernel<<<512, 256, 0, stream>>>(x, sp);
    conv_mfma<<<1024, 256, 0, stream>>>(sp, whi, wlo, y);
    upsample_kernel<<<32768, 256, 0, stream>>>(y, out);
}

// Round 3
// 108.070 us; speedup vs baseline: 1.3682x; 1.3682x over previous
//
#include <hip/hip_runtime.h>
#include <stdint.h>

constexpr int Bn = 8, Cn = 64, Hn = 128, Wn = 128;
constexpr int HsC = 64, WsC = 64;
constexpr int Kn = 256;                 // C * r^2
constexpr int PX = HsC * WsC;           // 4096 pixels per (t,b) plane
constexpr float DECAYF = 0.25f;

typedef __attribute__((ext_vector_type(8))) short short8v;
typedef __attribute__((ext_vector_type(4))) float f32x4;

static __device__ __forceinline__ ushort f2bf_rn(float f) {
    uint32_t u = __float_as_uint(f);
    uint32_t r = (u + 0x7FFFu + ((u >> 16) & 1u)) >> 16;
    return (ushort)r;
}
static __device__ __forceinline__ float bf2f(ushort u) {
    return __uint_as_float(((uint32_t)u) << 16);
}

// u8 spikes (0..4) -> 8 bf16 via v_perm byte-LUT (exact). Verified round 2.
// bf16: 0->0x0000 1->0x3F80 2->0x4000 3->0x4040 4->0x4080
static __device__ __forceinline__ short8v unpack8(uint32_t s0, uint32_t s1) {
    uint32_t lo0 = __builtin_amdgcn_perm(0x00000080u, 0x40008000u, s0);
    uint32_t hi0 = __builtin_amdgcn_perm(0x00000040u, 0x40403F00u, s0);
    uint32_t lo1 = __builtin_amdgcn_perm(0x00000080u, 0x40008000u, s1);
    uint32_t hi1 = __builtin_amdgcn_perm(0x00000040u, 0x40403F00u, s1);
    union { uint32_t u[4]; short8v s; } r;
    r.u[0] = __builtin_amdgcn_perm(hi0, lo0, 0x05010400u);
    r.u[1] = __builtin_amdgcn_perm(hi0, lo0, 0x07030602u);
    r.u[2] = __builtin_amdgcn_perm(hi1, lo1, 0x05010400u);
    r.u[3] = __builtin_amdgcn_perm(hi1, lo1, 0x07030602u);
    return r.s;
}

// ---------------------------------------------------------------------------
// Kernel 0: weight prep — fold /4 dequant, split into bf16 hi + lo
// ---------------------------------------------------------------------------
__global__ __launch_bounds__(256) void wprep_kernel(const float* __restrict__ w,
                                                    ushort* __restrict__ wh,
                                                    ushort* __restrict__ wl) {
    int i = blockIdx.x * 256 + threadIdx.x;     // 16384 total
    float wq = w[i] * 0.25f;
    ushort h = f2bf_rn(wq);
    float hf = bf2f(h);
    wh[i] = h;
    wl[i] = f2bf_rn(wq - hf);
}

// ---------------------------------------------------------------------------
// Fused LIF + 1x1 conv (at low res; conv commutes with bilinear upsample).
// Block = 512 threads, owns (b, hs row, ws half): 32 px x all 64 input c.
//   LIF: thread = (cg 0..15 -> 4 channels, pxl 0..31). Reads coalesced.
//   Spikes -> LDS [px][k], XOR-swizzled at 16B granule.
//   MFMA: 8 waves = 4 c_out-tiles x 2 px-tiles; K=256, hi/lo bf16 weights.
//   y tile staged in LDS -> coalesced bf16 global writes.
// ---------------------------------------------------------------------------
__global__ __launch_bounds__(512) void fused_lif_conv(const float* __restrict__ x,
                                                      const ushort* __restrict__ wh,
                                                      const ushort* __restrict__ wl,
                                                      ushort* __restrict__ y) {
    __shared__ __align__(16) uint8_t sp_lds[32 * 256];   // 8 KB
    __shared__ __align__(8)  uint8_t y_lds[32 * 128];    // 4 KB  [px][c] bf16

    const int tid  = threadIdx.x;
    const int pxl  = tid & 31;          // local pixel (ws within half)
    const int cg   = tid >> 5;          // 0..15, channels cg*4..cg*4+3
    const int lane = tid & 63;
    const int wid  = tid >> 6;          // 0..7
    const int l15  = lane & 15;
    const int g    = lane >> 4;
    const int wc   = wid & 3;           // c_out tile (16 c)
    const int wp   = wid >> 2;          // px tile (16 px)

    const int bid  = blockIdx.x;        // 1024 = 8 b x 64 hs x 2 half
    const int half = bid & 1;
    const int hs   = (bid >> 1) & 63;
    const int b    = bid >> 7;

    const int ws_abs = half * 32 + pxl;
    const int c0 = cg * 4;

    const size_t tstr = (size_t)Bn * Cn * Hn * Wn;
    const float* xb = x + ((size_t)b * Cn + c0) * (Hn * Wn) + (2 * hs) * Wn + 2 * ws_abs;

    float mem[4] = {0.f, 0.f, 0.f, 0.f}, spk[4] = {0.f, 0.f, 0.f, 0.f};
    float2 r0[4], r1[4];
    #pragma unroll
    for (int ci = 0; ci < 4; ++ci) {
        r0[ci] = *(const float2*)(xb + ci * (Hn * Wn));
        r1[ci] = *(const float2*)(xb + ci * (Hn * Wn) + Wn);
    }

    const int spw  = pxl * 256 + ((cg * 16) ^ ((pxl & 15) << 4));  // spike write addr
    const int bpx  = wp * 16 + l15;                                 // MFMA B pixel
    const int arow = wc * 16 + l15;                                 // MFMA A row (c_out)
    const ushort* whp = wh + arow * Kn;
    const ushort* wlp = wl + arow * Kn;
    const int cb   = wc * 4 + g;                                    // c_out quad idx
    const int ywb  = bpx * 128 + ((cb * 8) ^ ((bpx & 7) << 3));     // y_lds write addr
    const int crow = tid >> 3;          // writeout: c row 0..63
    const int pq   = tid & 7;           // writeout: px quad 0..7

    #pragma unroll
    for (int t = 0; t < 4; ++t) {
        // ---- LIF: 4 sub-steps (p = i*2+j time order) for 4 channels ----
        uint32_t pk[4];
        #pragma unroll
        for (int ci = 0; ci < 4; ++ci) {
            float m = mem[ci], s = spk[ci], sv;
            uint32_t p;
            m = (m - s) * DECAYF + r0[ci].x;
            sv = rintf(fminf(fmaxf(m, 0.f), 4.f)); s = sv * 0.25f; p = (uint32_t)(int)sv;
            m = (m - s) * DECAYF + r0[ci].y;
            sv = rintf(fminf(fmaxf(m, 0.f), 4.f)); s = sv * 0.25f; p |= ((uint32_t)(int)sv) << 8;
            m = (m - s) * DECAYF + r1[ci].x;
            sv = rintf(fminf(fmaxf(m, 0.f), 4.f)); s = sv * 0.25f; p |= ((uint32_t)(int)sv) << 16;
            m = (m - s) * DECAYF + r1[ci].y;
            sv = rintf(fminf(fmaxf(m, 0.f), 4.f)); s = sv * 0.25f; p |= ((uint32_t)(int)sv) << 24;
            mem[ci] = m; spk[ci] = s; pk[ci] = p;
        }
        // ---- prefetch next t's x under the conv phase ----
        if (t < 3) {
            const float* xn = xb + (size_t)(t + 1) * tstr;
            #pragma unroll
            for (int ci = 0; ci < 4; ++ci) {
                r0[ci] = *(const float2*)(xn + ci * (Hn * Wn));
                r1[ci] = *(const float2*)(xn + ci * (Hn * Wn) + Wn);
            }
        }
        // ---- spikes -> LDS (16B per thread, swizzled) ----
        *(uint4*)(sp_lds + spw) = make_uint4(pk[0], pk[1], pk[2], pk[3]);
        __syncthreads();

        // ---- MFMA: y[c_out][px] = sum_k wq[c_out][k] * sp[px][k] ----
        f32x4 acc = {0.f, 0.f, 0.f, 0.f};
        #pragma unroll
        for (int ks = 0; ks < 8; ++ks) {
            int k0 = ks * 32 + g * 8;
            short8v ah = *(const short8v*)(whp + k0);
            short8v al = *(const short8v*)(wlp + k0);
            int rb = bpx * 256 + (k0 ^ ((bpx & 15) << 4));
            uint2 sv2 = *(const uint2*)(sp_lds + rb);
            short8v bf = unpack8(sv2.x, sv2.y);
            acc = __builtin_amdgcn_mfma_f32_16x16x32_bf16(ah, bf, acc, 0, 0, 0);
            acc = __builtin_amdgcn_mfma_f32_16x16x32_bf16(al, bf, acc, 0, 0, 0);
        }
        __syncthreads();   // sp_lds fully consumed

        // ---- epilogue: acc -> y_lds [px][c] (C/D: col=l15=px, row=g*4+r=c) ----
        uint32_t lo = (uint32_t)f2bf_rn(acc[0]) | ((uint32_t)f2bf_rn(acc[1]) << 16);
        uint32_t hi = (uint32_t)f2bf_rn(acc[2]) | ((uint32_t)f2bf_rn(acc[3]) << 16);
        *(uint2*)(y_lds + ywb) = make_uint2(lo, hi);
        __syncthreads();

        // ---- coalesced y writeout: thread = (crow, pq) -> 4 px bf16 ----
        ushort v[4];
        #pragma unroll
        for (int j = 0; j < 4; ++j) {
            int pxj = pq * 4 + j;
            int addr = pxj * 128 + (((crow >> 2) * 8) ^ ((pxj & 7) << 3)) + (crow & 3) * 2;
            v[j] = *(const ushort*)(y_lds + addr);
        }
        uint2 o = make_uint2((uint32_t)v[0] | ((uint32_t)v[1] << 16),
                             (uint32_t)v[2] | ((uint32_t)v[3] << 16));
        ushort* yg = y + ((size_t)(t * Bn + b) * Cn + crow) * PX + hs * 64 + half * 32 + pq * 4;
        *(uint2*)yg = o;
        __syncthreads();   // y_lds safe to rewrite next t (also orders sp_lds reuse)
    }
}

// ---------------------------------------------------------------------------
// Kernel 3: bilinear 2x upsample from bf16 y, half-pixel centers, edge clamp
// ---------------------------------------------------------------------------
__global__ __launch_bounds__(256) void upsample_kernel(const ushort* __restrict__ y,
                                                       float* __restrict__ out) {
    int gg = blockIdx.x * 256 + threadIdx.x;   // 8388608 threads
    int wq = gg & 31;                // output col quad: w0 = 4*wq
    int h  = (gg >> 5) & 127;
    int rr = gg >> 12;
    int c  = rr & 63;
    int tb = rr >> 6;

    const ushort* yp = y + ((size_t)tb * Cn + c) * PX;

    int m = h >> 1;
    int r0, r1; float v0, v1;
    if ((h & 1) == 0) { r0 = (m - 1 < 0) ? 0 : (m - 1); r1 = m; v0 = 0.25f; v1 = 0.75f; }
    else              { r0 = m; r1 = (m + 1 > 63) ? 63 : (m + 1); v0 = 0.75f; v1 = 0.25f; }

    int ca = (2 * wq - 1 < 0) ? 0 : (2 * wq - 1);
    int cbx = 2 * wq;
    int cc = 2 * wq + 1;
    int cd = (2 * wq + 2 > 63) ? 63 : (2 * wq + 2);

    const ushort* ra = yp + r0 * WsC;
    const ushort* rb = yp + r1 * WsC;
    float a0 = bf2f(ra[ca]), b0 = bf2f(ra[cbx]), e0 = bf2f(ra[cc]), d0 = bf2f(ra[cd]);
    float a1 = bf2f(rb[ca]), b1 = bf2f(rb[cbx]), e1 = bf2f(rb[cc]), d1 = bf2f(rb[cd]);

    float h00 = 0.25f * a0 + 0.75f * b0;
    float h01 = 0.75f * b0 + 0.25f * e0;
    float h02 = 0.25f * b0 + 0.75f * e0;
    float h03 = 0.75f * e0 + 0.25f * d0;
    float h10 = 0.25f * a1 + 0.75f * b1;
    float h11 = 0.75f * b1 + 0.25f * e1;
    float h12 = 0.25f * b1 + 0.75f * e1;
    float h13 = 0.75f * e1 + 0.25f * d1;

    float4 o;
    o.x = v0 * h00 + v1 * h10;
    o.y = v0 * h01 + v1 * h11;
    o.z = v0 * h02 + v1 * h12;
    o.w = v0 * h03 + v1 * h13;

    *(float4*)(out + ((size_t)tb * Cn + c) * (Hn * Wn) + (size_t)h * Wn + 4 * wq) = o;
}

// ---------------------------------------------------------------------------
extern "C" void kernel_launch(void* const* d_in, const int* in_sizes, int n_in,
                              void* d_out, int out_size, void* d_ws, size_t ws_size,
                              hipStream_t stream) {
    const float* x = (const float*)d_in[0];
    const float* w = (const float*)d_in[1];
    float* out = (float*)d_out;

    ushort* y   = (ushort*)d_ws;                                  // 16,777,216 B
    ushort* whi = (ushort*)((uint8_t*)d_ws + (size_t)16777216);   // 32,768 B
    ushort* wlo = (ushort*)((uint8_t*)d_ws + (size_t)16809984);   // 32,768 B

    wprep_kernel<<<64, 256, 0, stream>>>(w, whi, wlo);
    fused_lif_conv<<<1024, 512, 0, stream>>>(x, whi, wlo, y);
    upsample_kernel<<<32768, 256, 0, stream>>>(y, out);
}